// Round 2
// baseline (1033.429 us; speedup 1.0000x reference)
//
#include <hip/hip_runtime.h>

// MonotoneiResBlock: B=131072 rows, D=64, H=256.
//   forward:  w <- sqrt2*x - tanh(w@W1)@W2   (10 iters; Lip~0.49, ref's 100 iters converge long before)
//   y = sqrt2*w - x
//   logdet = -2 * eps . J(eps + J^2 eps + J^4 eps + J^6 eps + J^8 eps),  J v = (sech^2(w@W1) o (v@W1)) @ W2
// All GEMMs as transposed MFMA (U^T = W1^T Z^T, G^T = W2^T H^T) with a shared K-permutation pi so the
// D-fragment of one GEMM is directly the B-fragment of the next (no LDS for activations, no barriers).
// d_out is FLOAT32: y = 131072*64 floats, then logdet = 131072 floats.

typedef __attribute__((ext_vector_type(8))) short bf16x8;
typedef __attribute__((ext_vector_type(4))) float f32x4;
typedef __attribute__((ext_vector_type(4))) unsigned int u32x4;

#define SQRT2F 1.41421356237309515f
#define NITER 10

__device__ __forceinline__ unsigned int pack2(float a, float b) {
    unsigned int ua = __builtin_bit_cast(unsigned int, a);
    unsigned int ub = __builtin_bit_cast(unsigned int, b);
    return ((ua + 0x8000u) >> 16) | ((ub + 0x8000u) & 0xFFFF0000u);
}
__device__ __forceinline__ float fast_tanh(float xx) {
    // tanh(x) = 1 - 2/(1+e^{2x}); exp overflow/underflow saturate correctly (inf->1, 0->-1)
    float a = __expf(xx + xx);
    float r = __builtin_amdgcn_rcpf(a + 1.0f);
    return fmaf(-2.0f, r, 1.0f);
}
__device__ __forceinline__ u32x4 packfrag(const float (&a)[4], const float (&b)[4]) {
    u32x4 r;
    r[0] = pack2(a[0], a[1]); r[1] = pack2(a[2], a[3]);
    r[2] = pack2(b[0], b[1]); r[3] = pack2(b[2], b[3]);
    return r;
}

// GEMM1: uacc[m0] (m0=0..15 tiles over H=256) = W1^T-tile x Z^T, K=64 (2 ksteps)
__device__ __forceinline__ void gemm1(const u32x4* sW1p, int lane, const u32x4 (&vb)[2], f32x4 (&uacc)[16]) {
#pragma unroll
    for (int m = 0; m < 16; ++m) { f32x4 z = {0.f, 0.f, 0.f, 0.f}; uacc[m] = z; }
#pragma unroll
    for (int kk = 0; kk < 2; ++kk) {
        bf16x8 bw = __builtin_bit_cast(bf16x8, vb[kk]);
#pragma unroll
        for (int m = 0; m < 16; ++m) {
            bf16x8 aw = __builtin_bit_cast(bf16x8, sW1p[(m * 2 + kk) * 64 + lane]);
            uacc[m] = __builtin_amdgcn_mfma_f32_16x16x32_bf16(aw, bw, uacc[m], 0, 0, 0);
        }
    }
}

// GEMM2: out[m0][r] (m0=0..3 tiles over D=64) = W2^T-tile x H^T, K=256 (8 ksteps)
__device__ __forceinline__ void gemm2(const u32x4* sW2p, int lane, const u32x4 (&hb)[8], float (&outv)[4][4]) {
    f32x4 g[4];
#pragma unroll
    for (int m = 0; m < 4; ++m) { f32x4 z = {0.f, 0.f, 0.f, 0.f}; g[m] = z; }
#pragma unroll
    for (int kk = 0; kk < 8; ++kk) {
        bf16x8 bh = __builtin_bit_cast(bf16x8, hb[kk]);
#pragma unroll
        for (int m = 0; m < 4; ++m) {
            bf16x8 aw = __builtin_bit_cast(bf16x8, sW2p[(m * 8 + kk) * 64 + lane]);
            g[m] = __builtin_amdgcn_mfma_f32_16x16x32_bf16(aw, bh, g[m], 0, 0, 0);
        }
    }
#pragma unroll
    for (int m = 0; m < 4; ++m)
#pragma unroll
        for (int r = 0; r < 4; ++r) outv[m][r] = g[m][r];
}

// jvp: out = (dd o (in @ W1)) @ W2   (in/out in the per-lane G^T layout: [m0][r] = dim 16*m0+4*q+r)
__device__ __forceinline__ void jvp_apply(const u32x4* sW1p, const u32x4* sW2p, int lane,
                                          const float (&dd)[16][4], const float (&in)[4][4],
                                          float (&outv)[4][4]) {
    u32x4 vb[2];
    vb[0] = packfrag(in[0], in[1]);
    vb[1] = packfrag(in[2], in[3]);
    f32x4 uacc[16];
    gemm1(sW1p, lane, vb, uacc);
    u32x4 hb[8];
#pragma unroll
    for (int mp = 0; mp < 8; ++mp) {
        float a0 = uacc[2 * mp][0] * dd[2 * mp][0];
        float a1 = uacc[2 * mp][1] * dd[2 * mp][1];
        float a2 = uacc[2 * mp][2] * dd[2 * mp][2];
        float a3 = uacc[2 * mp][3] * dd[2 * mp][3];
        float b0 = uacc[2 * mp + 1][0] * dd[2 * mp + 1][0];
        float b1 = uacc[2 * mp + 1][1] * dd[2 * mp + 1][1];
        float b2 = uacc[2 * mp + 1][2] * dd[2 * mp + 1][2];
        float b3 = uacc[2 * mp + 1][3] * dd[2 * mp + 1][3];
        hb[mp][0] = pack2(a0, a1); hb[mp][1] = pack2(a2, a3);
        hb[mp][2] = pack2(b0, b1); hb[mp][3] = pack2(b2, b3);
    }
    gemm2(sW2p, lane, hb, outv);
}

__global__ __launch_bounds__(512, 2) void monot_kernel(
    const float* __restrict__ x, const float* __restrict__ eps,
    const float* __restrict__ W1, const float* __restrict__ W2,
    float* __restrict__ out) {
    __shared__ u32x4 sW1p[2048];  // [m0(16)][kk(2)][lane(64)] A-frags of W1^T, pi-permuted K
    __shared__ u32x4 sW2p[2048];  // [m0(4)][kk(8)][lane(64)]  A-frags of W2^T

    const int tid = threadIdx.x;
    const int lane = tid & 63;
    const int wv = tid >> 6;  // 0..7
    const int c = lane & 15;
    const int q = lane >> 4;

    // ---- pack weights into LDS (A-fragment layout; pi(q,j) = 4q + (j&3) + 16*(j>>2)) ----
#pragma unroll
    for (int e0 = 0; e0 < 4; ++e0) {
        int idx = e0 * 512 + tid;  // W1 entries
        int l = idx & 63;
        int lq = l >> 4, lc = l & 15;
        int m0 = idx >> 7;
        int kk = (idx >> 6) & 1;
        float v[8];
#pragma unroll
        for (int j = 0; j < 8; ++j) {
            int kp = 32 * kk + 4 * lq + (j & 3) + ((j >> 2) << 4);
            v[j] = W1[kp * 256 + 16 * m0 + lc];  // W1^T[16m0+lc][kp]
        }
        u32x4 pk;
        pk[0] = pack2(v[0], v[1]); pk[1] = pack2(v[2], v[3]);
        pk[2] = pack2(v[4], v[5]); pk[3] = pack2(v[6], v[7]);
        sW1p[idx] = pk;
    }
#pragma unroll
    for (int e0 = 0; e0 < 4; ++e0) {
        int idx = e0 * 512 + tid;  // W2 entries
        int l = idx & 63;
        int lq = l >> 4, lc = l & 15;
        int m0 = idx >> 9;
        int kk = (idx >> 6) & 7;
        float v[8];
#pragma unroll
        for (int j = 0; j < 8; ++j) {
            int kp = 32 * kk + 4 * lq + (j & 3) + ((j >> 2) << 4);
            v[j] = W2[kp * 64 + 16 * m0 + lc];  // W2^T[16m0+lc][kp]
        }
        u32x4 pk;
        pk[0] = pack2(v[0], v[1]); pk[1] = pack2(v[2], v[3]);
        pk[2] = pack2(v[4], v[5]); pk[3] = pack2(v[6], v[7]);
        sW2p[idx] = pk;
    }
    __syncthreads();

    const int row = blockIdx.x * 128 + wv * 16 + c;  // this lane's batch row
    const float* xr = x + (size_t)row * 64;

    // lane holds dims d = 16*m + 4*q + r  (m=0..3, r=0..3) of its row
    float xw[4][4], w[4][4];
#pragma unroll
    for (int m = 0; m < 4; ++m) {
        f32x4 t = *(const f32x4*)(xr + 16 * m + 4 * q);
#pragma unroll
        for (int r = 0; r < 4; ++r) { xw[m][r] = t[r]; w[m][r] = SQRT2F * t[r]; }
    }

    // ---- fixed-point iterations ----
    for (int it = 0; it < NITER; ++it) {
        u32x4 vb[2];
        vb[0] = packfrag(w[0], w[1]);
        vb[1] = packfrag(w[2], w[3]);
        f32x4 uacc[16];
        gemm1(sW1p, lane, vb, uacc);
        u32x4 hb[8];
#pragma unroll
        for (int mp = 0; mp < 8; ++mp) {
            float t0 = fast_tanh(uacc[2 * mp][0]);
            float t1 = fast_tanh(uacc[2 * mp][1]);
            float t2 = fast_tanh(uacc[2 * mp][2]);
            float t3 = fast_tanh(uacc[2 * mp][3]);
            float u0 = fast_tanh(uacc[2 * mp + 1][0]);
            float u1 = fast_tanh(uacc[2 * mp + 1][1]);
            float u2 = fast_tanh(uacc[2 * mp + 1][2]);
            float u3 = fast_tanh(uacc[2 * mp + 1][3]);
            hb[mp][0] = pack2(t0, t1); hb[mp][1] = pack2(t2, t3);
            hb[mp][2] = pack2(u0, u1); hb[mp][3] = pack2(u2, u3);
        }
        float gout[4][4];
        gemm2(sW2p, lane, hb, gout);
#pragma unroll
        for (int m = 0; m < 4; ++m)
#pragma unroll
            for (int r = 0; r < 4; ++r) w[m][r] = fmaf(SQRT2F, xw[m][r], -gout[m][r]);
    }

    // ---- y = sqrt2*w - x (float32 out) ----
#pragma unroll
    for (int m = 0; m < 4; ++m) {
        f32x4 st;
#pragma unroll
        for (int r = 0; r < 4; ++r) st[r] = fmaf(SQRT2F, w[m][r], -xw[m][r]);
        *(f32x4*)(out + (size_t)row * 64 + 16 * m + 4 * q) = st;
    }

    // ---- load eps ----
    float ew[4][4];
    {
        const float* er = eps + (size_t)row * 64;
#pragma unroll
        for (int m = 0; m < 4; ++m) {
            f32x4 t = *(const f32x4*)(er + 16 * m + 4 * q);
#pragma unroll
            for (int r = 0; r < 4; ++r) ew[m][r] = t[r];
        }
    }

    // ---- d = sech^2(w@W1) at the converged w ----
    float dd[16][4];
    {
        u32x4 vb[2];
        vb[0] = packfrag(w[0], w[1]);
        vb[1] = packfrag(w[2], w[3]);
        f32x4 uacc[16];
        gemm1(sW1p, lane, vb, uacc);
#pragma unroll
        for (int m = 0; m < 16; ++m)
#pragma unroll
            for (int r = 0; r < 4; ++r) {
                float t = fast_tanh(uacc[m][r]);
                dd[m][r] = fmaf(-t, t, 1.0f);
            }
    }

    // ---- Neumann: s = eps + J^2 e + J^4 e + J^6 e + J^8 e; logdet = -2 * eps . (J s) ----
    float s[4][4], v[4][4];
#pragma unroll
    for (int m = 0; m < 4; ++m)
#pragma unroll
        for (int r = 0; r < 4; ++r) { s[m][r] = ew[m][r]; v[m][r] = ew[m][r]; }
    for (int k = 1; k <= 8; ++k) {
        jvp_apply(sW1p, sW2p, lane, dd, v, v);
        if ((k & 1) == 0) {
#pragma unroll
            for (int m = 0; m < 4; ++m)
#pragma unroll
                for (int r = 0; r < 4; ++r) s[m][r] += v[m][r];
        }
    }
    float tt[4][4];
    jvp_apply(sW1p, sW2p, lane, dd, s, tt);
    float p = 0.f;
#pragma unroll
    for (int m = 0; m < 4; ++m)
#pragma unroll
        for (int r = 0; r < 4; ++r) p = fmaf(ew[m][r], tt[m][r], p);
    p += __shfl_xor(p, 16);
    p += __shfl_xor(p, 32);
    p *= -2.0f;
    if (lane < 16) out[(size_t)8388608 + row] = p;
}

extern "C" void kernel_launch(void* const* d_in, const int* in_sizes, int n_in,
                              void* d_out, int out_size, void* d_ws, size_t ws_size,
                              hipStream_t stream) {
    const float* x = (const float*)d_in[0];
    const float* eps = (const float*)d_in[1];
    const float* W1 = (const float*)d_in[2];
    const float* W2 = (const float*)d_in[3];
    float* out = (float*)d_out;
    // 131072 rows / (8 waves * 16 rows) = 1024 blocks
    monot_kernel<<<dim3(1024), dim3(512), 0, stream>>>(x, eps, W1, W2, out);
}

// Round 3
// 715.204 us; speedup vs baseline: 1.4449x; 1.4449x over previous
//
#include <hip/hip_runtime.h>

// MonotoneiResBlock: B=131072 rows, D=64, H=256.
//   forward:  w <- sqrt2*x - tanh(w@W1)@W2   (10 iters; Lip~0.49, ref's 100 iters converge long before)
//   y = sqrt2*w - x
//   logdet = -2 * eps . J(eps + J^2 eps + J^4 eps + J^6 eps + J^8 eps),  J v = (sech^2(w@W1) o (v@W1)) @ W2
// Transposed MFMA GEMMs (U^T = W1^T Z^T, G^T = W2^T H^T), shared K-permutation pi so D-frag of one GEMM
// feeds the next as B-frag. Register-pressure discipline: GEMM1 fused per-16-wide-H-tile (acc = 4 regs,
// never 64), dd stored as packed bf16 (32 regs). No spills target: peak live ~115 VGPR.
// d_out is FLOAT32: y = 131072*64 floats, then logdet = 131072 floats.

typedef __attribute__((ext_vector_type(8))) short bf16x8;
typedef __attribute__((ext_vector_type(4))) float f32x4;
typedef __attribute__((ext_vector_type(4))) unsigned int u32x4;

#define SQRT2F 1.41421356237309515f
#define NITER 10

__device__ __forceinline__ unsigned int pack2(float a, float b) {
    unsigned int ua = __builtin_bit_cast(unsigned int, a);
    unsigned int ub = __builtin_bit_cast(unsigned int, b);
    return ((ua + 0x8000u) >> 16) | ((ub + 0x8000u) & 0xFFFF0000u);
}
__device__ __forceinline__ float bf_lo(unsigned int u) { return __builtin_bit_cast(float, u << 16); }
__device__ __forceinline__ float bf_hi(unsigned int u) { return __builtin_bit_cast(float, u & 0xFFFF0000u); }
__device__ __forceinline__ float fast_tanh(float xx) {
    // tanh(x) = 1 - 2/(1+e^{2x}); exp saturates correctly (inf->1, 0->-1)
    float a = __expf(xx + xx);
    float r = __builtin_amdgcn_rcpf(a + 1.0f);
    return fmaf(-2.0f, r, 1.0f);
}
__device__ __forceinline__ u32x4 packfrag(const float (&a)[4], const float (&b)[4]) {
    u32x4 r;
    r[0] = pack2(a[0], a[1]); r[1] = pack2(a[2], a[3]);
    r[2] = pack2(b[0], b[1]); r[3] = pack2(b[2], b[3]);
    return r;
}

// GEMM2: outv[m][r] (dim 16m+4q+r) = W2^T-tile x H^T, K=256 (8 ksteps), g[4] = 16 regs live
__device__ __forceinline__ void gemm2(const u32x4* sW2p, int lane, const u32x4 (&hb)[8], float (&outv)[4][4]) {
    f32x4 g[4];
#pragma unroll
    for (int m = 0; m < 4; ++m) { f32x4 z = {0.f, 0.f, 0.f, 0.f}; g[m] = z; }
#pragma unroll
    for (int kk = 0; kk < 8; ++kk) {
        bf16x8 bh = __builtin_bit_cast(bf16x8, hb[kk]);
#pragma unroll
        for (int m = 0; m < 4; ++m) {
            bf16x8 aw = __builtin_bit_cast(bf16x8, sW2p[(m * 8 + kk) * 64 + lane]);
            g[m] = __builtin_amdgcn_mfma_f32_16x16x32_bf16(aw, bh, g[m], 0, 0, 0);
        }
    }
#pragma unroll
    for (int m = 0; m < 4; ++m)
#pragma unroll
        for (int r = 0; r < 4; ++r) outv[m][r] = g[m][r];
}

// jvp: out = (dd o (in @ W1)) @ W2, dd packed bf16 in dpk. GEMM1 fused per-m (acc = 4 regs).
__device__ __forceinline__ void jvp_apply(const u32x4* sW1p, const u32x4* sW2p, int lane,
                                          const unsigned int (&dpk)[16][2], const float (&in)[4][4],
                                          float (&outv)[4][4]) {
    u32x4 vb0 = packfrag(in[0], in[1]);
    u32x4 vb1 = packfrag(in[2], in[3]);
    bf16x8 bw0 = __builtin_bit_cast(bf16x8, vb0);
    bf16x8 bw1 = __builtin_bit_cast(bf16x8, vb1);
    u32x4 hb[8];
#pragma unroll
    for (int mp = 0; mp < 8; ++mp) {
#pragma unroll
        for (int sub = 0; sub < 2; ++sub) {
            const int m = 2 * mp + sub;
            f32x4 acc = {0.f, 0.f, 0.f, 0.f};
            acc = __builtin_amdgcn_mfma_f32_16x16x32_bf16(
                __builtin_bit_cast(bf16x8, sW1p[(m * 2 + 0) * 64 + lane]), bw0, acc, 0, 0, 0);
            acc = __builtin_amdgcn_mfma_f32_16x16x32_bf16(
                __builtin_bit_cast(bf16x8, sW1p[(m * 2 + 1) * 64 + lane]), bw1, acc, 0, 0, 0);
            float h0 = acc[0] * bf_lo(dpk[m][0]);
            float h1 = acc[1] * bf_hi(dpk[m][0]);
            float h2 = acc[2] * bf_lo(dpk[m][1]);
            float h3 = acc[3] * bf_hi(dpk[m][1]);
            hb[mp][2 * sub + 0] = pack2(h0, h1);
            hb[mp][2 * sub + 1] = pack2(h2, h3);
        }
    }
    gemm2(sW2p, lane, hb, outv);
}

__global__ __launch_bounds__(512, 2) void monot_kernel(
    const float* __restrict__ x, const float* __restrict__ eps,
    const float* __restrict__ W1, const float* __restrict__ W2,
    float* __restrict__ out) {
    __shared__ u32x4 sW1p[2048];  // [m0(16)][kk(2)][lane(64)] A-frags of W1^T, pi-permuted K
    __shared__ u32x4 sW2p[2048];  // [m0(4)][kk(8)][lane(64)]  A-frags of W2^T

    const int tid = threadIdx.x;
    const int lane = tid & 63;
    const int wv = tid >> 6;  // 0..7
    const int c = lane & 15;
    const int q = lane >> 4;

    // ---- pack weights into LDS (A-fragment layout; pi(q,j) = 4q + (j&3) + 16*(j>>2)) ----
#pragma unroll
    for (int e0 = 0; e0 < 4; ++e0) {
        int idx = e0 * 512 + tid;  // W1 entries
        int l = idx & 63;
        int lq = l >> 4, lc = l & 15;
        int m0 = idx >> 7;
        int kk = (idx >> 6) & 1;
        float v[8];
#pragma unroll
        for (int j = 0; j < 8; ++j) {
            int kp = 32 * kk + 4 * lq + (j & 3) + ((j >> 2) << 4);
            v[j] = W1[kp * 256 + 16 * m0 + lc];  // W1^T[16m0+lc][kp]
        }
        u32x4 pk;
        pk[0] = pack2(v[0], v[1]); pk[1] = pack2(v[2], v[3]);
        pk[2] = pack2(v[4], v[5]); pk[3] = pack2(v[6], v[7]);
        sW1p[idx] = pk;
    }
#pragma unroll
    for (int e0 = 0; e0 < 4; ++e0) {
        int idx = e0 * 512 + tid;  // W2 entries
        int l = idx & 63;
        int lq = l >> 4, lc = l & 15;
        int m0 = idx >> 9;
        int kk = (idx >> 6) & 7;
        float v[8];
#pragma unroll
        for (int j = 0; j < 8; ++j) {
            int kp = 32 * kk + 4 * lq + (j & 3) + ((j >> 2) << 4);
            v[j] = W2[kp * 64 + 16 * m0 + lc];  // W2^T[16m0+lc][kp]
        }
        u32x4 pk;
        pk[0] = pack2(v[0], v[1]); pk[1] = pack2(v[2], v[3]);
        pk[2] = pack2(v[4], v[5]); pk[3] = pack2(v[6], v[7]);
        sW2p[idx] = pk;
    }
    __syncthreads();

    const int row = blockIdx.x * 128 + wv * 16 + c;  // this lane's batch row
    const float* xr = x + (size_t)row * 64;

    // lane holds dims d = 16*m + 4*q + r  (m=0..3, r=0..3) of its row
    float xw[4][4], w[4][4];
#pragma unroll
    for (int m = 0; m < 4; ++m) {
        f32x4 t = *(const f32x4*)(xr + 16 * m + 4 * q);
#pragma unroll
        for (int r = 0; r < 4; ++r) { xw[m][r] = t[r]; w[m][r] = SQRT2F * t[r]; }
    }

    // ---- fixed-point iterations ----
#pragma unroll 1
    for (int it = 0; it < NITER; ++it) {
        u32x4 vb0 = packfrag(w[0], w[1]);
        u32x4 vb1 = packfrag(w[2], w[3]);
        bf16x8 bw0 = __builtin_bit_cast(bf16x8, vb0);
        bf16x8 bw1 = __builtin_bit_cast(bf16x8, vb1);
        u32x4 hb[8];
#pragma unroll
        for (int mp = 0; mp < 8; ++mp) {
#pragma unroll
            for (int sub = 0; sub < 2; ++sub) {
                const int m = 2 * mp + sub;
                f32x4 acc = {0.f, 0.f, 0.f, 0.f};
                acc = __builtin_amdgcn_mfma_f32_16x16x32_bf16(
                    __builtin_bit_cast(bf16x8, sW1p[(m * 2 + 0) * 64 + lane]), bw0, acc, 0, 0, 0);
                acc = __builtin_amdgcn_mfma_f32_16x16x32_bf16(
                    __builtin_bit_cast(bf16x8, sW1p[(m * 2 + 1) * 64 + lane]), bw1, acc, 0, 0, 0);
                float t0 = fast_tanh(acc[0]);
                float t1 = fast_tanh(acc[1]);
                float t2 = fast_tanh(acc[2]);
                float t3 = fast_tanh(acc[3]);
                hb[mp][2 * sub + 0] = pack2(t0, t1);
                hb[mp][2 * sub + 1] = pack2(t2, t3);
            }
        }
        float gout[4][4];
        gemm2(sW2p, lane, hb, gout);
#pragma unroll
        for (int m = 0; m < 4; ++m)
#pragma unroll
            for (int r = 0; r < 4; ++r) w[m][r] = fmaf(SQRT2F, xw[m][r], -gout[m][r]);
    }

    // ---- y = sqrt2*w - x (float32 out) ----
#pragma unroll
    for (int m = 0; m < 4; ++m) {
        f32x4 st;
#pragma unroll
        for (int r = 0; r < 4; ++r) st[r] = fmaf(SQRT2F, w[m][r], -xw[m][r]);
        *(f32x4*)(out + (size_t)row * 64 + 16 * m + 4 * q) = st;
    }

    // ---- d = sech^2(w@W1) at converged w, packed to bf16 (32 regs) ----
    unsigned int dpk[16][2];
    {
        u32x4 vb0 = packfrag(w[0], w[1]);
        u32x4 vb1 = packfrag(w[2], w[3]);
        bf16x8 bw0 = __builtin_bit_cast(bf16x8, vb0);
        bf16x8 bw1 = __builtin_bit_cast(bf16x8, vb1);
#pragma unroll
        for (int m = 0; m < 16; ++m) {
            f32x4 acc = {0.f, 0.f, 0.f, 0.f};
            acc = __builtin_amdgcn_mfma_f32_16x16x32_bf16(
                __builtin_bit_cast(bf16x8, sW1p[(m * 2 + 0) * 64 + lane]), bw0, acc, 0, 0, 0);
            acc = __builtin_amdgcn_mfma_f32_16x16x32_bf16(
                __builtin_bit_cast(bf16x8, sW1p[(m * 2 + 1) * 64 + lane]), bw1, acc, 0, 0, 0);
            float t0 = fast_tanh(acc[0]);
            float t1 = fast_tanh(acc[1]);
            float t2 = fast_tanh(acc[2]);
            float t3 = fast_tanh(acc[3]);
            dpk[m][0] = pack2(fmaf(-t0, t0, 1.0f), fmaf(-t1, t1, 1.0f));
            dpk[m][1] = pack2(fmaf(-t2, t2, 1.0f), fmaf(-t3, t3, 1.0f));
        }
    }

    // ---- load eps ----
    float ew[4][4];
    {
        const float* er = eps + (size_t)row * 64;
#pragma unroll
        for (int m = 0; m < 4; ++m) {
            f32x4 t = *(const f32x4*)(er + 16 * m + 4 * q);
#pragma unroll
            for (int r = 0; r < 4; ++r) ew[m][r] = t[r];
        }
    }

    // ---- Neumann: s = eps + J^2 e + J^4 e + J^6 e + J^8 e; logdet = -2 * eps . (J s) ----
    float s[4][4], v[4][4];
#pragma unroll
    for (int m = 0; m < 4; ++m)
#pragma unroll
        for (int r = 0; r < 4; ++r) { s[m][r] = ew[m][r]; v[m][r] = ew[m][r]; }
#pragma unroll 1
    for (int k = 1; k <= 8; ++k) {
        jvp_apply(sW1p, sW2p, lane, dpk, v, v);
        if ((k & 1) == 0) {
#pragma unroll
            for (int m = 0; m < 4; ++m)
#pragma unroll
                for (int r = 0; r < 4; ++r) s[m][r] += v[m][r];
        }
    }
    float tt[4][4];
    jvp_apply(sW1p, sW2p, lane, dpk, s, tt);
    float p = 0.f;
#pragma unroll
    for (int m = 0; m < 4; ++m)
#pragma unroll
        for (int r = 0; r < 4; ++r) p = fmaf(ew[m][r], tt[m][r], p);
    p += __shfl_xor(p, 16);
    p += __shfl_xor(p, 32);
    p *= -2.0f;
    if (lane < 16) out[(size_t)8388608 + row] = p;
}

extern "C" void kernel_launch(void* const* d_in, const int* in_sizes, int n_in,
                              void* d_out, int out_size, void* d_ws, size_t ws_size,
                              hipStream_t stream) {
    const float* x = (const float*)d_in[0];
    const float* eps = (const float*)d_in[1];
    const float* W1 = (const float*)d_in[2];
    const float* W2 = (const float*)d_in[3];
    float* out = (float*)d_out;
    // 131072 rows / (8 waves * 16 rows) = 1024 blocks
    monot_kernel<<<dim3(1024), dim3(512), 0, stream>>>(x, eps, W1, W2, out);
}